// Round 1
// baseline (377.576 us; speedup 1.0000x reference)
//
#include <hip/hip_runtime.h>
#include <math.h>

#define B_N 8
#define C_CH 128
#define H_IN 256
#define W_IN 256
#define HO 129
#define WO 129
#define SP (HO*WO)          // 16641
#define HIDDEN 11
#define NSTRIP 5
#define STRIP_H 26

__constant__ float c_lo[4] = {-0.12940952255126037f, 0.2241438680420134f,
                               0.8365163037378079f,  0.48296291314453416f};
__constant__ float c_hi[4] = {-0.48296291314453416f, 0.8365163037378079f,
                              -0.2241438680420134f, -0.12940952255126037f};

// -------- Kernel 1: DWT2 per (b,c,strip) + per-strip partial reductions -----
__global__ __launch_bounds__(256) void dwt_kernel(
    const float* __restrict__ x,
    float* __restrict__ cA, float* __restrict__ cH,
    float* __restrict__ psum, float* __restrict__ pmax)
{
  int blk   = blockIdx.x;
  int strip = blk % NSTRIP;
  int bc    = blk / NSTRIP;

  int j0 = strip * STRIP_H;
  int j1 = min(j0 + STRIP_H, HO);
  int rlo = max(0, 2*j0 - 2);
  int rhi = min(H_IN - 1, 2*j1 - 1);
  int nrows = rhi - rlo + 1;          // <= 54

  __shared__ float low[54 * WO];
  __shared__ float s_sum[4];
  __shared__ float s_max[4];

  const float* xp = x + (size_t)bc * (H_IN * W_IN);
  int tid = threadIdx.x;

  // horizontal low-pass: low[lr][j] = sum_m lo[m] * x[rlo+lr, refl(2j+1-m)]
  int tot = nrows * WO;
  for (int e = tid; e < tot; e += 256) {
    int lr = e / WO;
    int j  = e - lr * WO;
    const float* row = xp + (size_t)(rlo + lr) * W_IN;
    float acc = 0.f;
    int tb = 2*j + 1;
    #pragma unroll
    for (int m = 0; m < 4; ++m) {
      int t = tb - m;
      t = (t < 0) ? (-1 - t) : ((t > W_IN-1) ? (2*W_IN - 1 - t) : t);
      acc += c_lo[m] * row[t];
    }
    low[e] = acc;
  }
  __syncthreads();

  // vertical pass -> cA (lo), cH (hi); accumulate strip sum(cA), max(cH)
  float sumA = 0.f;
  float maxH = -INFINITY;
  int nj = j1 - j0;
  int tot2 = nj * WO;
  float* cAp = cA + (size_t)bc * SP;
  float* cHp = cH + (size_t)bc * SP;
  for (int e = tid; e < tot2; e += 256) {
    int lj  = e / WO;
    int col = e - lj * WO;
    int j   = j0 + lj;
    float a = 0.f, hv = 0.f;
    int tb = 2*j + 1;
    #pragma unroll
    for (int m = 0; m < 4; ++m) {
      int t = tb - m;
      t = (t < 0) ? (-1 - t) : ((t > H_IN-1) ? (2*H_IN - 1 - t) : t);
      float v = low[(t - rlo) * WO + col];
      a  += c_lo[m] * v;
      hv += c_hi[m] * v;
    }
    cAp[(size_t)j * WO + col] = a;
    cHp[(size_t)j * WO + col] = hv;
    sumA += a;
    maxH = fmaxf(maxH, hv);
  }

  // block reduction (deterministic within block)
  for (int off = 32; off > 0; off >>= 1) {
    sumA += __shfl_down(sumA, off, 64);
    maxH = fmaxf(maxH, __shfl_down(maxH, off, 64));
  }
  int wave = tid >> 6;
  if ((tid & 63) == 0) { s_sum[wave] = sumA; s_max[wave] = maxH; }
  __syncthreads();
  if (tid == 0) {
    float ss = s_sum[0] + s_sum[1] + s_sum[2] + s_sum[3];
    float mm = fmaxf(fmaxf(s_max[0], s_max[1]), fmaxf(s_max[2], s_max[3]));
    psum[bc * NSTRIP + strip] = ss;
    pmax[bc * NSTRIP + strip] = mm;
  }
}

// -------- Kernel 2: per-(b,spatial) mean/max over 256 channels --------------
__global__ __launch_bounds__(256) void chanstat_kernel(
    const float* __restrict__ cA, const float* __restrict__ cH,
    float* __restrict__ sa_in)
{
  int b = blockIdx.y;
  int s = blockIdx.x * 256 + threadIdx.x;
  if (s >= SP) return;
  const float* pa = cA + (size_t)b * C_CH * SP + s;
  const float* ph = cH + (size_t)b * C_CH * SP + s;
  float sum = 0.f, mx = -INFINITY;
  #pragma unroll 4
  for (int c = 0; c < C_CH; ++c) {
    float va = pa[(size_t)c * SP];
    float vh = ph[(size_t)c * SP];
    sum += va + vh;
    mx = fmaxf(mx, fmaxf(va, vh));
  }
  sa_in[(size_t)b * 2 * SP + s]      = sum * (1.f / 256.f);
  sa_in[(size_t)b * 2 * SP + SP + s] = mx;
}

// -------- Kernel 3: channel-attention MLP -----------------------------------
__global__ __launch_bounds__(128) void mlp_kernel(
    const float* __restrict__ psum, const float* __restrict__ pmax,
    const float* __restrict__ w1, const float* __restrict__ b1,
    const float* __restrict__ w2, const float* __restrict__ b2,
    float* __restrict__ att)
{
  int b = blockIdx.x;
  int c = threadIdx.x;   // 128 threads
  __shared__ float p[C_CH];
  __shared__ float h[HIDDEN];

  float s = 0.f, m = -INFINITY;
  #pragma unroll
  for (int k = 0; k < NSTRIP; ++k) {
    s += psum[(b * C_CH + c) * NSTRIP + k];
    m = fmaxf(m, pmax[(b * C_CH + c) * NSTRIP + k]);
  }
  p[c] = s * (1.f / 16641.f) + m;
  __syncthreads();

  if (c < HIDDEN) {
    float acc = b1[c];
    for (int k = 0; k < C_CH; ++k) acc += p[k] * w1[k * HIDDEN + c];
    h[c] = fmaxf(acc, 0.f);
  }
  __syncthreads();

  float acc = b2[c];
  #pragma unroll
  for (int j = 0; j < HIDDEN; ++j) acc += h[j] * w2[j * C_CH + c];
  att[b * C_CH + c] = 1.f / (1.f + expf(-acc));
}

// -------- Kernel 4: 5x5 conv (2->1 ch, zero pad) + sigmoid ------------------
__global__ __launch_bounds__(256) void conv_kernel(
    const float* __restrict__ sa_in, const float* __restrict__ w_sa,
    float* __restrict__ sa)
{
  int b = blockIdx.y;
  int s = blockIdx.x * 256 + threadIdx.x;
  if (s >= SP) return;
  int i = s / WO;
  int j = s - i * WO;
  float acc = 0.f;
  const float* in0 = sa_in + (size_t)b * 2 * SP;
  #pragma unroll
  for (int ch = 0; ch < 2; ++ch) {
    const float* in = in0 + ch * SP;
    #pragma unroll
    for (int u = 0; u < 5; ++u) {
      int ii = i + u - 2;
      if (ii < 0 || ii >= HO) continue;
      #pragma unroll
      for (int v = 0; v < 5; ++v) {
        int jj = j + v - 2;
        if (jj < 0 || jj >= WO) continue;
        acc += in[ii * WO + jj] * w_sa[(ch * 5 + u) * 5 + v];
      }
    }
  }
  sa[(size_t)b * SP + s] = 1.f / (1.f + expf(-acc));
}

// -------- Kernel 5: out = x * att[b,c] * bilinear_resize(sa) ----------------
__global__ __launch_bounds__(256) void final_kernel(
    const float* __restrict__ x, const float* __restrict__ att,
    const float* __restrict__ sa, float* __restrict__ out)
{
  int idx = blockIdx.x * 256 + threadIdx.x;   // one float4 per thread
  int j4  = idx & 63;                          // W/4 = 64
  int rem = idx >> 6;
  int I   = rem & 255;
  int bc  = rem >> 8;                          // 0..1023
  int b   = bc >> 7;

  float a = att[bc];

  float ti = (I + 0.5f) * (129.f / 256.f) - 0.5f;
  ti = fminf(fmaxf(ti, 0.f), 128.f);
  int i0 = (int)ti;
  float fi = ti - (float)i0;
  int i1 = min(i0 + 1, 128);
  const float* r0 = sa + ((size_t)b * HO + i0) * WO;
  const float* r1 = sa + ((size_t)b * HO + i1) * WO;

  float4 xv = reinterpret_cast<const float4*>(x)[idx];
  float res[4];
  #pragma unroll
  for (int q = 0; q < 4; ++q) {
    int J = j4 * 4 + q;
    float tj = (J + 0.5f) * (129.f / 256.f) - 0.5f;
    tj = fminf(fmaxf(tj, 0.f), 128.f);
    int jj0 = (int)tj;
    float fj = tj - (float)jj0;
    int jj1 = min(jj0 + 1, 128);
    float v0 = r0[jj0] + fj * (r0[jj1] - r0[jj0]);
    float v1 = r1[jj0] + fj * (r1[jj1] - r1[jj0]);
    res[q] = v0 + fi * (v1 - v0);
  }
  float4 ov;
  ov.x = xv.x * a * res[0];
  ov.y = xv.y * a * res[1];
  ov.z = xv.z * a * res[2];
  ov.w = xv.w * a * res[3];
  reinterpret_cast<float4*>(out)[idx] = ov;
}

extern "C" void kernel_launch(void* const* d_in, const int* in_sizes, int n_in,
                              void* d_out, int out_size, void* d_ws, size_t ws_size,
                              hipStream_t stream) {
  const float* x    = (const float*)d_in[0];
  const float* w1   = (const float*)d_in[1];
  const float* b1   = (const float*)d_in[2];
  const float* w2   = (const float*)d_in[3];
  const float* b2   = (const float*)d_in[4];
  const float* w_sa = (const float*)d_in[5];
  float* out = (float*)d_out;

  // workspace layout (floats)
  float* cA    = (float*)d_ws;                         // B*C*SP
  float* cH    = cA + (size_t)B_N * C_CH * SP;         // B*C*SP
  float* psum  = cH + (size_t)B_N * C_CH * SP;         // B*C*NSTRIP
  float* pmax  = psum + B_N * C_CH * NSTRIP;           // B*C*NSTRIP
  float* sa_in = pmax + B_N * C_CH * NSTRIP;           // B*2*SP
  float* att   = sa_in + (size_t)B_N * 2 * SP;         // B*C
  float* sa    = att + B_N * C_CH;                     // B*SP

  hipLaunchKernelGGL(dwt_kernel, dim3(B_N * C_CH * NSTRIP), dim3(256), 0, stream,
                     x, cA, cH, psum, pmax);
  hipLaunchKernelGGL(chanstat_kernel, dim3((SP + 255) / 256, B_N), dim3(256), 0, stream,
                     cA, cH, sa_in);
  hipLaunchKernelGGL(mlp_kernel, dim3(B_N), dim3(C_CH), 0, stream,
                     psum, pmax, w1, b1, w2, b2, att);
  hipLaunchKernelGGL(conv_kernel, dim3((SP + 255) / 256, B_N), dim3(256), 0, stream,
                     sa_in, w_sa, sa);
  hipLaunchKernelGGL(final_kernel, dim3((B_N * C_CH * H_IN * W_IN / 4) / 256), dim3(256), 0, stream,
                     x, att, sa, out);
}

// Round 2
// 273.387 us; speedup vs baseline: 1.3811x; 1.3811x over previous
//
#include <hip/hip_runtime.h>
#include <math.h>

#define B_N 8
#define C_CH 128
#define H_IN 256
#define W_IN 256
#define HO 129
#define WO 129
#define SP (HO*WO)          // 16641
#define HIDDEN 11
#define NSTRIP 10
#define STRIP_H 13
#define MAXROWS 28

__constant__ float c_lo[4] = {-0.12940952255126037f, 0.2241438680420134f,
                               0.8365163037378079f,  0.48296291314453416f};
__constant__ float c_hi[4] = {-0.48296291314453416f, 0.8365163037378079f,
                              -0.2241438680420134f, -0.12940952255126037f};

// -------- Kernel 1: DWT2 per (b,c,strip) + per-strip partial reductions -----
// Stage x strip into LDS (float4 coalesced), h-pass from LDS, v-pass, write
// cA/cH, and per-strip sum(cA)/max(cH).
__global__ __launch_bounds__(256) void dwt_kernel(
    const float* __restrict__ x,
    float* __restrict__ cA, float* __restrict__ cH,
    float* __restrict__ psum, float* __restrict__ pmax)
{
  int blk   = blockIdx.x;
  int strip = blk % NSTRIP;
  int bc    = blk / NSTRIP;

  int j0 = strip * STRIP_H;
  int j1 = min(j0 + STRIP_H, HO);
  int rlo = max(0, 2*j0 - 2);
  int rhi = min(H_IN - 1, 2*j1 - 1);
  int nrows = rhi - rlo + 1;          // <= 28

  __shared__ float xs[MAXROWS * W_IN];     // 28*256*4 = 28672 B
  __shared__ float low[MAXROWS * WO];      // 28*129*4 = 14448 B
  __shared__ float s_sum[4];
  __shared__ float s_max[4];

  int tid = threadIdx.x;

  // stage x rows [rlo..rhi] into LDS, float4 coalesced
  {
    const float4* xp4 = reinterpret_cast<const float4*>(x + (size_t)bc * (H_IN * W_IN));
    float4* xs4 = reinterpret_cast<float4*>(xs);
    int tot4 = nrows * (W_IN / 4);
    for (int e = tid; e < tot4; e += 256) {
      int row = e >> 6;          // W_IN/4 = 64
      int c4  = e & 63;
      xs4[e] = xp4[(size_t)(rlo + row) * 64 + c4];
    }
  }
  __syncthreads();

  // horizontal low-pass from LDS: low[lr][j] = sum_m lo[m]*xs[lr][refl(2j+1-m)]
  int tot = nrows * WO;
  for (int e = tid; e < tot; e += 256) {
    int lr = e / WO;
    int j  = e - lr * WO;
    const float* row = xs + lr * W_IN;
    float acc = 0.f;
    int tb = 2*j + 1;
    #pragma unroll
    for (int m = 0; m < 4; ++m) {
      int t = tb - m;
      t = (t < 0) ? (-1 - t) : ((t > W_IN-1) ? (2*W_IN - 1 - t) : t);
      acc += c_lo[m] * row[t];
    }
    low[lr * WO + j] = acc;
  }
  __syncthreads();

  // vertical pass -> cA (lo), cH (hi); accumulate strip sum(cA), max(cH)
  float sumA = 0.f;
  float maxH = -INFINITY;
  int nj = j1 - j0;
  int tot2 = nj * WO;
  float* cAp = cA + (size_t)bc * SP;
  float* cHp = cH + (size_t)bc * SP;
  for (int e = tid; e < tot2; e += 256) {
    int lj  = e / WO;
    int col = e - lj * WO;
    int j   = j0 + lj;
    float a = 0.f, hv = 0.f;
    int tb = 2*j + 1;
    #pragma unroll
    for (int m = 0; m < 4; ++m) {
      int t = tb - m;
      t = (t < 0) ? (-1 - t) : ((t > H_IN-1) ? (2*H_IN - 1 - t) : t);
      float v = low[(t - rlo) * WO + col];
      a  += c_lo[m] * v;
      hv += c_hi[m] * v;
    }
    cAp[(size_t)j * WO + col] = a;
    cHp[(size_t)j * WO + col] = hv;
    sumA += a;
    maxH = fmaxf(maxH, hv);
  }

  // block reduction (deterministic within block)
  for (int off = 32; off > 0; off >>= 1) {
    sumA += __shfl_down(sumA, off, 64);
    maxH = fmaxf(maxH, __shfl_down(maxH, off, 64));
  }
  int wave = tid >> 6;
  if ((tid & 63) == 0) { s_sum[wave] = sumA; s_max[wave] = maxH; }
  __syncthreads();
  if (tid == 0) {
    float ss = s_sum[0] + s_sum[1] + s_sum[2] + s_sum[3];
    float mm = fmaxf(fmaxf(s_max[0], s_max[1]), fmaxf(s_max[2], s_max[3]));
    psum[bc * NSTRIP + strip] = ss;
    pmax[bc * NSTRIP + strip] = mm;
  }
}

// -------- Kernel 2: per-(b,spatial) mean/max over 256 channels --------------
__global__ __launch_bounds__(256) void chanstat_kernel(
    const float* __restrict__ cA, const float* __restrict__ cH,
    float* __restrict__ sa_in)
{
  int b = blockIdx.y;
  int s = blockIdx.x * 256 + threadIdx.x;
  if (s >= SP) return;
  const float* pa = cA + (size_t)b * C_CH * SP + s;
  const float* ph = cH + (size_t)b * C_CH * SP + s;
  float sum = 0.f, mx = -INFINITY;
  #pragma unroll 4
  for (int c = 0; c < C_CH; ++c) {
    float va = pa[(size_t)c * SP];
    float vh = ph[(size_t)c * SP];
    sum += va + vh;
    mx = fmaxf(mx, fmaxf(va, vh));
  }
  sa_in[(size_t)b * 2 * SP + s]      = sum * (1.f / 256.f);
  sa_in[(size_t)b * 2 * SP + SP + s] = mx;
}

// -------- Kernel 3: channel-attention MLP -----------------------------------
__global__ __launch_bounds__(128) void mlp_kernel(
    const float* __restrict__ psum, const float* __restrict__ pmax,
    const float* __restrict__ w1, const float* __restrict__ b1,
    const float* __restrict__ w2, const float* __restrict__ b2,
    float* __restrict__ att)
{
  int b = blockIdx.x;
  int c = threadIdx.x;   // 128 threads
  __shared__ float p[C_CH];
  __shared__ float h[HIDDEN];

  float s = 0.f, m = -INFINITY;
  #pragma unroll
  for (int k = 0; k < NSTRIP; ++k) {
    s += psum[(b * C_CH + c) * NSTRIP + k];
    m = fmaxf(m, pmax[(b * C_CH + c) * NSTRIP + k]);
  }
  p[c] = s * (1.f / 16641.f) + m;
  __syncthreads();

  if (c < HIDDEN) {
    float acc = b1[c];
    for (int k = 0; k < C_CH; ++k) acc += p[k] * w1[k * HIDDEN + c];
    h[c] = fmaxf(acc, 0.f);
  }
  __syncthreads();

  float acc = b2[c];
  #pragma unroll
  for (int j = 0; j < HIDDEN; ++j) acc += h[j] * w2[j * C_CH + c];
  att[b * C_CH + c] = 1.f / (1.f + expf(-acc));
}

// -------- Kernel 4: 5x5 conv (2->1 ch, zero pad) + sigmoid ------------------
__global__ __launch_bounds__(256) void conv_kernel(
    const float* __restrict__ sa_in, const float* __restrict__ w_sa,
    float* __restrict__ sa)
{
  int b = blockIdx.y;
  int s = blockIdx.x * 256 + threadIdx.x;
  if (s >= SP) return;
  int i = s / WO;
  int j = s - i * WO;
  float acc = 0.f;
  const float* in0 = sa_in + (size_t)b * 2 * SP;
  #pragma unroll
  for (int ch = 0; ch < 2; ++ch) {
    const float* in = in0 + ch * SP;
    #pragma unroll
    for (int u = 0; u < 5; ++u) {
      int ii = i + u - 2;
      if (ii < 0 || ii >= HO) continue;
      #pragma unroll
      for (int v = 0; v < 5; ++v) {
        int jj = j + v - 2;
        if (jj < 0 || jj >= WO) continue;
        acc += in[ii * WO + jj] * w_sa[(ch * 5 + u) * 5 + v];
      }
    }
  }
  sa[(size_t)b * SP + s] = 1.f / (1.f + expf(-acc));
}

// -------- Kernel 4b: bilinear resize sa (8,129,129) -> sar (8,256,256) ------
__global__ __launch_bounds__(256) void resize_kernel(
    const float* __restrict__ sa, float* __restrict__ sar)
{
  int idx = blockIdx.x * 256 + threadIdx.x;   // 8*256*256 = 524288
  int J = idx & 255;
  int I = (idx >> 8) & 255;
  int b = idx >> 16;

  float ti = (I + 0.5f) * (129.f / 256.f) - 0.5f;
  ti = fminf(fmaxf(ti, 0.f), 128.f);
  int i0 = (int)ti;
  float fi = ti - (float)i0;
  int i1 = min(i0 + 1, 128);

  float tj = (J + 0.5f) * (129.f / 256.f) - 0.5f;
  tj = fminf(fmaxf(tj, 0.f), 128.f);
  int jj0 = (int)tj;
  float fj = tj - (float)jj0;
  int jj1 = min(jj0 + 1, 128);

  const float* r0 = sa + ((size_t)b * HO + i0) * WO;
  const float* r1 = sa + ((size_t)b * HO + i1) * WO;
  float v0 = r0[jj0] + fj * (r0[jj1] - r0[jj0]);
  float v1 = r1[jj0] + fj * (r1[jj1] - r1[jj0]);
  sar[idx] = v0 + fi * (v1 - v0);
}

// -------- Kernel 5: out = x * att[b,c] * sar (pure stream) ------------------
__global__ __launch_bounds__(256) void final2_kernel(
    const float* __restrict__ x, const float* __restrict__ att,
    const float* __restrict__ sar, float* __restrict__ out)
{
  // bid = ((b*64 + rg)*4 + cchunk); block: 4 rows x 256 cols x 32 channels
  int bid = blockIdx.x;
  int cchunk = bid & 3;
  int rg  = (bid >> 2) & 63;
  int b   = bid >> 8;
  int t = threadIdx.x;
  int r = t >> 6;          // 0..3
  int col4 = t & 63;
  int I = rg * 4 + r;

  __shared__ float att_s[32];
  if (t < 32) att_s[t] = att[b * C_CH + cchunk * 32 + t];
  __syncthreads();

  float4 sv = reinterpret_cast<const float4*>(sar + ((size_t)b * 256 + I) * 256)[col4];

  size_t base4 = ((size_t)(b * C_CH + cchunk * 32) * 256 + I) * 64 + col4;
  const float4* xp = reinterpret_cast<const float4*>(x);
  float4* op = reinterpret_cast<float4*>(out);
  #pragma unroll 4
  for (int cc = 0; cc < 32; ++cc) {
    float a = att_s[cc];
    float4 xv = xp[base4 + (size_t)cc * 16384];
    float4 ov;
    ov.x = xv.x * a * sv.x;
    ov.y = xv.y * a * sv.y;
    ov.z = xv.z * a * sv.z;
    ov.w = xv.w * a * sv.w;
    op[base4 + (size_t)cc * 16384] = ov;
  }
}

extern "C" void kernel_launch(void* const* d_in, const int* in_sizes, int n_in,
                              void* d_out, int out_size, void* d_ws, size_t ws_size,
                              hipStream_t stream) {
  const float* x    = (const float*)d_in[0];
  const float* w1   = (const float*)d_in[1];
  const float* b1   = (const float*)d_in[2];
  const float* w2   = (const float*)d_in[3];
  const float* b2   = (const float*)d_in[4];
  const float* w_sa = (const float*)d_in[5];
  float* out = (float*)d_out;

  // workspace layout (floats)
  float* cA    = (float*)d_ws;                         // B*C*SP
  float* cH    = cA + (size_t)B_N * C_CH * SP;         // B*C*SP
  float* psum  = cH + (size_t)B_N * C_CH * SP;         // B*C*NSTRIP
  float* pmax  = psum + B_N * C_CH * NSTRIP;           // B*C*NSTRIP
  float* sa_in = pmax + B_N * C_CH * NSTRIP;           // B*2*SP
  float* att   = sa_in + (size_t)B_N * 2 * SP;         // B*C
  float* sa    = att + B_N * C_CH;                     // B*SP
  // sar aliases cA: cA/cH are dead after chanstat_kernel; resize runs later.
  float* sar   = cA;                                   // B*256*256 (2 MB)

  hipLaunchKernelGGL(dwt_kernel, dim3(B_N * C_CH * NSTRIP), dim3(256), 0, stream,
                     x, cA, cH, psum, pmax);
  hipLaunchKernelGGL(chanstat_kernel, dim3((SP + 255) / 256, B_N), dim3(256), 0, stream,
                     cA, cH, sa_in);
  hipLaunchKernelGGL(mlp_kernel, dim3(B_N), dim3(C_CH), 0, stream,
                     psum, pmax, w1, b1, w2, b2, att);
  hipLaunchKernelGGL(conv_kernel, dim3((SP + 255) / 256, B_N), dim3(256), 0, stream,
                     sa_in, w_sa, sa);
  hipLaunchKernelGGL(resize_kernel, dim3(B_N * H_IN * W_IN / 256), dim3(256), 0, stream,
                     sa, sar);
  hipLaunchKernelGGL(final2_kernel, dim3(B_N * 64 * 4), dim3(256), 0, stream,
                     x, att, sar, out);
}